// Round 4
// baseline (611.252 us; speedup 1.0000x reference)
//
#include <hip/hip_runtime.h>
#include <hip/hip_bf16.h>

typedef float f32x4 __attribute__((ext_vector_type(4)));
typedef __bf16 bf16x8 __attribute__((ext_vector_type(8)));
typedef unsigned short u16x4 __attribute__((ext_vector_type(4)));

#if defined(__has_builtin)
#if __has_builtin(__builtin_amdgcn_exp2f)
#define EXP2F(x) __builtin_amdgcn_exp2f(x)
#else
#define EXP2F(x) exp2f(x)
#endif
#if __has_builtin(__builtin_amdgcn_rcpf)
#define RCPF(x) __builtin_amdgcn_rcpf(x)
#else
#define RCPF(x) (1.0f/(x))
#endif
#else
#define EXP2F(x) exp2f(x)
#define RCPF(x) (1.0f/(x))
#endif

#define MFMA16(a,b,c) __builtin_amdgcn_mfma_f32_16x16x32_bf16((a),(b),(c),0,0,0)

__device__ __forceinline__ unsigned short f2bf(float f) {
  return __builtin_bit_cast(unsigned short, (__bf16)f);
}

// Build permuted W1^T in d_ws: W1Tg[rho][iota], bf16.
//   rho: jb=rho>>5, jf=(rho>>4)&1, a=(rho>>2)&3, c=rho&3  -> j = jb*32 + a*8 + jf*4 + c   [pi]
//   iota: kb=io>>5,  u=(io>>3)&3,  v=io&7                 -> i = kb*32 + (v>>2)*16 + u*4 + (v&3)  [sigma]
__global__ __launch_bounds__(256) void hn_prep(const float* __restrict__ W1,
                                               unsigned short* __restrict__ W1T) {
  int t = blockIdx.x * 256 + threadIdx.x;  // t = rho*128 + iota
  int rho = t >> 7, io = t & 127;
  int j = (rho >> 5) * 32 + ((rho >> 2) & 3) * 8 + ((rho >> 4) & 1) * 4 + (rho & 3);
  int i = (io >> 5) * 32 + ((io & 7) >> 2) * 16 + ((io >> 3) & 3) * 4 + (io & 7 & 3);
  W1T[t] = f2bf(W1[i * 512 + j]);
}

// One block = 256 batch rows (16 waves x 16 rows), 1024 threads -> 4 waves/SIMD.
// Zero cross-lane exchanges: pi/sigma permutations align C-layouts with frag layouts.
__global__ __launch_bounds__(1024, 4) void hn_main(
    const float* __restrict__ x, const float* __restrict__ W1,
    const float* __restrict__ b1, const float* __restrict__ W2,
    const unsigned short* __restrict__ W1T, float* __restrict__ out) {
  __shared__ __align__(16) char w1l[131072];  // W1 bf16 [128 i][512 j] natural, ^((i&7)<<4)
  __shared__ __align__(16) float b1s[512];    // b1 * 2*log2(e)
  __shared__ __align__(16) float w2s[512];

  const int tid = threadIdx.x;
  const int lane = tid & 63;
  const int w = tid >> 6;      // 0..15
  const int m = lane & 15;
  const int g = lane >> 4;

  // ---- stage natural W1 -> LDS (bwd A-frags: j-contiguous 16B runs)
  for (int it = tid; it < 16384; it += 1024) {
    int flat = it << 2;            // element index = i*512 + j
    int i = flat >> 9;
    f32x4 v = *(const f32x4*)(W1 + flat);
    u16x4 pk;
#pragma unroll
    for (int c = 0; c < 4; ++c) pk[c] = f2bf(v[c]);
    int ba = flat << 1;
    *(u16x4*)(w1l + (ba ^ ((i & 7) << 4))) = pk;
  }
  if (tid < 512) {
    b1s[tid] = b1[tid] * 2.8853900817779268f;
    w2s[tid] = W2[tid];
  }
  __syncthreads();

  const int b0 = blockIdx.x * 256 + w * 16;
  const float* xrow = x + (long)(b0 + m) * 256;

  // q/p in sigma layout: q[kb][r] = (row b0+m, i = 32kb + 16*(r>>2) + 4g + (r&3))
  float q[4][8], p[4][8];
#pragma unroll
  for (int kb = 0; kb < 4; ++kb) {
    const float* r0 = xrow + kb * 32 + g * 4;
#pragma unroll
    for (int h = 0; h < 2; ++h) {
      f32x4 qv = *(const f32x4*)(r0 + h * 16);
      f32x4 pv = *(const f32x4*)(r0 + h * 16 + 128);
#pragma unroll
      for (int rr = 0; rr < 4; ++rr) {
        q[kb][4 * h + rr] = qv[rr];
        p[kb][4 * h + rr] = pv[rr];
      }
    }
  }

  // lane-constant bases
  const char* aptr = (const char*)W1T + m * 256 + g * 16;  // fwd A: row rho=..+m, iota-chunk
  const int s45 = (m & 3) << 4, s6 = (m & 4) << 4;
  const int ybase = ((m * 1024 + g * 16) ^ s45);            // bwd A from LDS

#pragma unroll 1
  for (int step = 0; step < 10; ++step) {
    f32x4 gacc[8];  // C: col b = m, row i = 16nf + 4g + rr
#pragma unroll
    for (int nf = 0; nf < 8; ++nf) gacc[nf] = f32x4{0.f, 0.f, 0.f, 0.f};

#pragma unroll 2
    for (int jblk = 0; jblk < 16; ++jblk) {
      // ---- forward: z tile. A = W1Tg rows (pi-ordered j), B = q (sigma order).
      f32x4 z[2];
      z[0] = f32x4{0.f, 0.f, 0.f, 0.f};
      z[1] = f32x4{0.f, 0.f, 0.f, 0.f};
#pragma unroll
      for (int kb = 0; kb < 4; ++kb) {
        bf16x8 qb;
#pragma unroll
        for (int r = 0; r < 8; ++r) qb[r] = (__bf16)q[kb][r];
#pragma unroll
        for (int jf = 0; jf < 2; ++jf) {
          bf16x8 a = *(const bf16x8*)(aptr + jblk * 8192 + jf * 4096 + kb * 64);
          z[jf] = MFMA16(a, qb, z[jf]);
        }
      }
      // ---- activation: s = W2[j] * sech^2(z + b1[j]); z C-row (jf,rr) <-> j = 32jblk+8g+4jf+rr
      bf16x8 sB;
#pragma unroll
      for (int jf = 0; jf < 2; ++jf) {
        f32x4 b1v = *(const f32x4*)(b1s + jblk * 32 + g * 8 + jf * 4);
        f32x4 w2v = *(const f32x4*)(w2s + jblk * 32 + g * 8 + jf * 4);
#pragma unroll
        for (int rr = 0; rr < 4; ++rr) {
          float zz = fmaf(z[jf][rr], 2.8853900817779268f, b1v[rr]);
          float e = EXP2F(zz);                 // e^(2(z+b1))
          float u = RCPF(e + 1.f);
          float th = fmaf(-2.f, u, 1.f);       // tanh
          sB[jf * 4 + rr] = (__bf16)fmaf(-th * th, w2v[rr], w2v[rr]);
        }
      }
      // ---- backward: gacc += W1(A, natural from LDS) * s^T(B). k order = natural j.
      const int joff = (jblk * 64) ^ s6;
#pragma unroll
      for (int nf = 0; nf < 8; ++nf) {
        bf16x8 af = *(const bf16x8*)(w1l + ybase + nf * 16384 + joff);
        gacc[nf] = MFMA16(af, sB, gacc[nf]);
      }
    }

    // q += dt * p_old  (gacc was computed from old q)
#pragma unroll
    for (int kb = 0; kb < 4; ++kb)
#pragma unroll
      for (int r = 0; r < 8; ++r)
        q[kb][r] = fmaf(0.1f, p[kb][r], q[kb][r]);

    // p -= dt * g : gacc C-layout == p sigma-frag layout, pure f32, static indices
#pragma unroll
    for (int kb = 0; kb < 4; ++kb)
#pragma unroll
      for (int r = 0; r < 8; ++r)
        p[kb][r] = fmaf(-0.1f, gacc[2 * kb + (r >> 2)][r & 3], p[kb][r]);

    __syncthreads();  // phase-lock waves (L1 locality on W1Tg slices)
  }

  // ---- store concat(q, p) with the same sigma addressing
  float* orow = out + (long)(b0 + m) * 256;
#pragma unroll
  for (int kb = 0; kb < 4; ++kb) {
    float* o = orow + kb * 32 + g * 4;
#pragma unroll
    for (int h = 0; h < 2; ++h) {
      f32x4 qv, pv;
#pragma unroll
      for (int rr = 0; rr < 4; ++rr) {
        qv[rr] = q[kb][4 * h + rr];
        pv[rr] = p[kb][4 * h + rr];
      }
      *(f32x4*)(o + h * 16) = qv;
      *(f32x4*)(o + h * 16 + 128) = pv;
    }
  }
}

extern "C" void kernel_launch(void* const* d_in, const int* in_sizes, int n_in,
                              void* d_out, int out_size, void* d_ws, size_t ws_size,
                              hipStream_t stream) {
  const float* x  = (const float*)d_in[0];
  const float* W1 = (const float*)d_in[1];
  const float* b1 = (const float*)d_in[2];
  const float* W2 = (const float*)d_in[3];
  // d_in[4] = b2: affects only V's value, not its gradient -> unused.
  float* out = (float*)d_out;
  unsigned short* w1t = (unsigned short*)d_ws;  // 128 KB bf16 permuted W1^T

  hipLaunchKernelGGL(hn_prep, dim3(256), dim3(256), 0, stream, W1, w1t);
  hipLaunchKernelGGL(hn_main, dim3(256), dim3(1024), 0, stream,
                     x, W1, b1, W2, w1t, out);
}